// Round 2
// baseline (157.400 us; speedup 1.0000x reference)
//
#include <hip/hip_runtime.h>

#define NB 256
#define NA 64
#define NG 978
#define CELL_IN 978
#define DOSE_IN 12
#define GLOBAL_F 306
#define EXP_IN 434
#define NE 4

#define NBATCH 4
#define B_BLOCKS (NB / NBATCH)          // 64
#define A_BLOCKS 256                    // 16 tiles x 4 experts x 4 h-quarters
#define AB_GRID  (B_BLOCKS + A_BLOCKS)  // 320 blocks

// ---- workspace layout (float offsets) ----
// v4[tile16][e4][q=h/4 (32)][g64][4h]
#define WS_SEL 0                       // [256][4] : e1, e2, gate1, gate2
#define WS_U   (WS_SEL + NB*4)         // [256][2][128]
#define WS_V   (WS_U + NB*256)         // 524288 floats

// ---- shared memory: one aliased buffer (61.2 KB -> 2 blocks/CU) ----
#define SMEM_F 15296
// b-part carve (batch-transposed activations: x[k][4])
#define O_GEXT 0        // [978][4]  = 3912
#define O_GT   3912     // [306][4]  = 1224
#define O_H1T  5136     // [200][4]  = 800
#define O_H2T  5936     // [100][4]  = 400
#define O_D1   6336     // [4][64]   = 256
#define O_GH   6592     // [4][128]  = 512
#define O_PART 7104     // 8192 reduction scratch
// a-part carve
#define O_GENE 0        // 64*129 = 8256
#define O_PUA  8256     // [2][512][4] = 4096

__device__ __forceinline__ float wave_reduce(float p) {
    #pragma unroll
    for (int off = 32; off > 0; off >>= 1) p += __shfl_down(p, off, 64);
    return p;
}

__device__ __forceinline__ float rfl(float x) {
    return __int_as_float(__builtin_amdgcn_readfirstlane(__float_as_int(x)));
}

// ---------------------------------------------------------------------------
// AB kernel.
//   blocks [0,64):   b-part — 4 batches per block, weights read ONCE per
//                    block, activations batch-transposed in LDS so one
//                    ds_read_b128 broadcasts all 4 batches.
//   blocks [64,320): a-part — v4 producer (proven, unchanged).
// ---------------------------------------------------------------------------
__global__ __launch_bounds__(1024) void ab_kernel(
    const float* __restrict__ drug, const float* __restrict__ gex,
    const float* __restrict__ idose,
    const float* __restrict__ cW1, const float* __restrict__ cb1,
    const float* __restrict__ cW2, const float* __restrict__ cb2,
    const float* __restrict__ cW3, const float* __restrict__ cb3,
    const float* __restrict__ dW1, const float* __restrict__ db1,
    const float* __restrict__ dW2, const float* __restrict__ db2,
    const float* __restrict__ gW1, const float* __restrict__ gb1,
    const float* __restrict__ gW2, const float* __restrict__ gb2,
    const float* __restrict__ eW1, const float* __restrict__ eb1,
    const float* __restrict__ gene,
    float* __restrict__ ws, float* __restrict__ cell_out)
{
    __shared__ float smem[SMEM_F];
    __shared__ int   s_isel[NBATCH][2];

    const int blk = blockIdx.x, tid = threadIdx.x;

    if (blk >= B_BLOCKS) {
        // ===== a-part: v4[tile][e][q][g][4], (tile,e,hq) per block =====
        float* s_gene = smem + O_GENE;
        float* s_pu_a = smem + O_PUA;
        const int ablk = blk - B_BLOCKS;           // 0..255
        const int tile = ablk >> 4, e = (ablk >> 2) & 3, hq = ablk & 3;

        for (int i = tid; i < 64 * 128; i += 1024) {
            int gl = i >> 7, k = i & 127;
            int g = tile * 64 + gl;
            s_gene[gl * 129 + k] = (g < NG) ? gene[g * 128 + k] : 0.f;
        }
        __syncthreads();

        const int g_in  = tid & 63;
        const int slice = (tid >> 6) & 7;          // 8 slices x 4h = 32 h
        const int khalf = tid >> 9;                // 2-way k split
        const int h0 = hq * 32 + slice * 4;
        const float* wbase = eW1
            + ((size_t)e * EXP_IN + GLOBAL_F + khalf * 64) * 128 + h0;
        float4 acc = {0.f, 0.f, 0.f, 0.f};
        #pragma unroll 8
        for (int k = 0; k < 64; ++k) {
            float x = s_gene[g_in * 129 + khalf * 64 + k];
            float4 w = *(const float4*)(wbase + (size_t)k * 128);
            acc.x += x * w.x; acc.y += x * w.y; acc.z += x * w.z; acc.w += x * w.w;
        }
        *(float4*)&s_pu_a[(khalf * 512 + slice * 64 + g_in) * 4] = acc;
        __syncthreads();
        if (khalf == 0) {
            float4 a0 = *(const float4*)&s_pu_a[(slice * 64 + g_in) * 4];
            float4 a1 = *(const float4*)&s_pu_a[(512 + slice * 64 + g_in) * 4];
            float4 r = {a0.x + a1.x, a0.y + a1.y, a0.z + a1.z, a0.w + a1.w};
            const int q = hq * 8 + slice;
            float* vout = ws + WS_V
                + ((size_t)(tile * 4 + e)) * 8192 + q * 256 + g_in * 4;
            *(float4*)vout = r;
        }
        return;
    }

    // ==================== b-part: 4 batches per block ======================
    const int b0 = blk * NBATCH;
    float* s_gexT = smem + O_GEXT;
    float* s_gT   = smem + O_GT;
    float* s_h1T  = smem + O_H1T;
    float* s_h2T  = smem + O_H2T;
    float* s_d1   = smem + O_D1;
    float* s_gh   = smem + O_GH;
    float* s_part = smem + O_PART;

    // ---- P0: stage gex (transposed), drug atom-partials ----
    #pragma unroll
    for (int bb = 0; bb < NBATCH; ++bb)
        for (int k = tid; k < CELL_IN; k += 1024)
            s_gexT[k * 4 + bb] = gex[(size_t)(b0 + bb) * CELL_IN + k];
    {
        int bl = tid >> 8, ah = (tid >> 7) & 1, d = tid & 127;
        const float* p = drug + ((size_t)(b0 + bl) * NA + ah * 32) * 128 + d;
        float acc = 0.f;
        #pragma unroll
        for (int i = 0; i < 32; ++i) acc += p[(size_t)i * 128];
        s_part[bl * 256 + ah * 128 + d] = acc;
    }
    __syncthreads();
    // ---- P0b: drug reduce -> s_gT[d][bl]; dose layer1 ----
    if (tid < 512) {
        int bl = tid >> 7, d = tid & 127;
        s_gT[d * 4 + bl] = s_part[bl * 256 + d] + s_part[bl * 256 + 128 + d];
    } else if (tid < 768) {
        int idx = tid - 512, bl = idx >> 6, j = idx & 63;
        float acc = db1[j];
        #pragma unroll
        for (int i = 0; i < DOSE_IN; ++i)
            acc += idose[(b0 + bl) * DOSE_IN + i] * dW1[i * 64 + j];
        s_d1[bl * 64 + j] = fmaxf(acc, 0.f);
    }
    __syncthreads();
    // ---- P0c: dose layer2 -> s_gT[178+j][bl] ----
    if (tid < 512) {
        int bl = tid >> 7, j = tid & 127;
        float acc = db2[j];
        #pragma unroll 8
        for (int i = 0; i < 64; ++i) acc += s_d1[bl * 64 + i] * dW2[i * 128 + j];
        s_gT[(178 + j) * 4 + bl] = fmaxf(acc, 0.f);
    }
    __syncthreads();

    // ---- P1: cell1 978->200 for 4 batches. w loaded once, 16 FMA/float4 ----
    if (tid < 512) {
        int ks = tid >> 6, q = tid & 63;           // 8 k-slices
        if (q < 50) {
            int k0 = ks * 123, k1 = min(k0 + 123, CELL_IN);
            float4 a0 = {0,0,0,0}, a1 = {0,0,0,0}, a2 = {0,0,0,0}, a3 = {0,0,0,0};
            #pragma unroll 4
            for (int k = k0; k < k1; ++k) {
                float4 x = *(const float4*)&s_gexT[k * 4];
                float4 w = *(const float4*)(cW1 + (size_t)k * 200 + 4 * q);
                a0.x += x.x * w.x; a0.y += x.x * w.y; a0.z += x.x * w.z; a0.w += x.x * w.w;
                a1.x += x.y * w.x; a1.y += x.y * w.y; a1.z += x.y * w.z; a1.w += x.y * w.w;
                a2.x += x.z * w.x; a2.y += x.z * w.y; a2.z += x.z * w.z; a2.w += x.z * w.w;
                a3.x += x.w * w.x; a3.y += x.w * w.y; a3.z += x.w * w.z; a3.w += x.w * w.w;
            }
            *(float4*)&s_part[(ks * 4 + 0) * 200 + 4 * q] = a0;
            *(float4*)&s_part[(ks * 4 + 1) * 200 + 4 * q] = a1;
            *(float4*)&s_part[(ks * 4 + 2) * 200 + 4 * q] = a2;
            *(float4*)&s_part[(ks * 4 + 3) * 200 + 4 * q] = a3;
        }
    }
    __syncthreads();
    {
        int b = tid >> 8, j = tid & 255;
        if (j < 200) {
            float a = cb1[j];
            #pragma unroll
            for (int ks = 0; ks < 8; ++ks) a += s_part[(ks * 4 + b) * 200 + j];
            s_h1T[j * 4 + b] = fmaxf(a, 0.f);
        }
    }
    __syncthreads();

    // ---- P2: cell2 200->100 ----
    if (tid < 512) {
        int ks = tid >> 5, q = tid & 31;           // 16 k-slices
        if (q < 25) {
            int k0 = ks * 13, k1 = min(k0 + 13, 200);
            float4 a0 = {0,0,0,0}, a1 = {0,0,0,0}, a2 = {0,0,0,0}, a3 = {0,0,0,0};
            #pragma unroll
            for (int k = k0; k < k1; ++k) {
                float4 x = *(const float4*)&s_h1T[k * 4];
                float4 w = *(const float4*)(cW2 + (size_t)k * 100 + 4 * q);
                a0.x += x.x * w.x; a0.y += x.x * w.y; a0.z += x.x * w.z; a0.w += x.x * w.w;
                a1.x += x.y * w.x; a1.y += x.y * w.y; a1.z += x.y * w.z; a1.w += x.y * w.w;
                a2.x += x.z * w.x; a2.y += x.z * w.y; a2.z += x.z * w.z; a2.w += x.z * w.w;
                a3.x += x.w * w.x; a3.y += x.w * w.y; a3.z += x.w * w.z; a3.w += x.w * w.w;
            }
            *(float4*)&s_part[(ks * 4 + 0) * 100 + 4 * q] = a0;
            *(float4*)&s_part[(ks * 4 + 1) * 100 + 4 * q] = a1;
            *(float4*)&s_part[(ks * 4 + 2) * 100 + 4 * q] = a2;
            *(float4*)&s_part[(ks * 4 + 3) * 100 + 4 * q] = a3;
        }
    }
    __syncthreads();
    if (tid < 512) {
        int b = tid >> 7, j = tid & 127;
        if (j < 100) {
            float a = cb2[j];
            #pragma unroll
            for (int ks = 0; ks < 16; ++ks) a += s_part[(ks * 4 + b) * 100 + j];
            s_h2T[j * 4 + b] = fmaxf(a, 0.f);
        }
    }
    __syncthreads();

    // ---- P3: cell3 100->50 ----
    {
        int ks = tid >> 8, b = (tid >> 6) & 3, j = tid & 63;
        if (j < 50) {
            int k0 = ks * 25, k1 = k0 + 25;
            float acc = 0.f;
            #pragma unroll
            for (int k = k0; k < k1; ++k) acc += s_h2T[k * 4 + b] * cW3[k * 50 + j];
            s_part[(ks * 4 + b) * 64 + j] = acc;
        }
    }
    __syncthreads();
    if (tid < 256) {
        int b = tid >> 6, j = tid & 63;
        if (j < 50) {
            float a = cb3[j];
            #pragma unroll
            for (int ks = 0; ks < 4; ++ks) a += s_part[(ks * 4 + b) * 64 + j];
            float r = fmaxf(a, 0.f);
            s_gT[(128 + j) * 4 + b] = r;
            cell_out[(b0 + b) * 50 + j] = r;
        }
    }
    __syncthreads();

    // ---- P4: gate1 306->128 ----
    if (tid < 512) {
        int ks = tid >> 5, q = tid & 31;           // 16 k-slices
        int k0 = ks * 20, k1 = min(k0 + 20, GLOBAL_F);
        float4 a0 = {0,0,0,0}, a1 = {0,0,0,0}, a2 = {0,0,0,0}, a3 = {0,0,0,0};
        #pragma unroll
        for (int k = k0; k < k1; ++k) {
            float4 x = *(const float4*)&s_gT[k * 4];
            float4 w = *(const float4*)(gW1 + (size_t)k * 128 + 4 * q);
            a0.x += x.x * w.x; a0.y += x.x * w.y; a0.z += x.x * w.z; a0.w += x.x * w.w;
            a1.x += x.y * w.x; a1.y += x.y * w.y; a1.z += x.y * w.z; a1.w += x.y * w.w;
            a2.x += x.z * w.x; a2.y += x.z * w.y; a2.z += x.z * w.z; a2.w += x.z * w.w;
            a3.x += x.w * w.x; a3.y += x.w * w.y; a3.z += x.w * w.z; a3.w += x.w * w.w;
        }
        *(float4*)&s_part[(ks * 4 + 0) * 128 + 4 * q] = a0;
        *(float4*)&s_part[(ks * 4 + 1) * 128 + 4 * q] = a1;
        *(float4*)&s_part[(ks * 4 + 2) * 128 + 4 * q] = a2;
        *(float4*)&s_part[(ks * 4 + 3) * 128 + 4 * q] = a3;
    }
    __syncthreads();
    if (tid < 512) {
        int b = tid >> 7, h = tid & 127;
        float a = gb1[h];
        #pragma unroll
        for (int ks = 0; ks < 16; ++ks) a += s_part[(ks * 4 + b) * 128 + h];
        s_gh[b * 128 + h] = fmaxf(a, 0.f);
    }
    __syncthreads();

    // ---- P5: logits + top-2 softmax (one wave per batch) ----
    if (tid < 256) {
        int bl = tid >> 6, lane = tid & 63;
        float h0 = s_gh[bl * 128 + lane], h1 = s_gh[bl * 128 + 64 + lane];
        float logit[NE];
        #pragma unroll
        for (int j = 0; j < NE; ++j) {
            float p = h0 * gW2[lane * NE + j] + h1 * gW2[(lane + 64) * NE + j];
            p = wave_reduce(p);
            logit[j] = p + gb2[j];
        }
        if (lane == 0) {
            int i1 = 0; float v1 = logit[0];
            #pragma unroll
            for (int i = 1; i < NE; ++i) if (logit[i] > v1) { v1 = logit[i]; i1 = i; }
            int i2 = -1; float v2 = -__builtin_inff();
            #pragma unroll
            for (int i = 0; i < NE; ++i) {
                if (i == i1) continue;
                if (logit[i] > v2) { v2 = logit[i]; i2 = i; }
            }
            float ex = __expf(v2 - v1);
            float inv = 1.f / (1.f + ex);
            s_isel[bl][0] = i1; s_isel[bl][1] = i2;
            int bg = b0 + bl;
            ws[WS_SEL + bg * 4 + 0] = (float)i1;
            ws[WS_SEL + bg * 4 + 1] = (float)i2;
            ws[WS_SEL + bg * 4 + 2] = inv;
            ws[WS_SEL + bg * 4 + 3] = ex * inv;
        }
    }
    __syncthreads();

    // ---- P6: u for the 2 ACTIVE experts of each batch ----
    {
        int bl = tid >> 8, es = (tid >> 7) & 1, ks = (tid >> 5) & 3, q = tid & 31;
        int e = s_isel[bl][es];
        int k0 = ks * 77, k1 = min(k0 + 77, GLOBAL_F);
        const float* wp = eW1 + (size_t)e * EXP_IN * 128 + 4 * q;
        float4 acc = {0,0,0,0};
        #pragma unroll 4
        for (int k = k0; k < k1; ++k) {
            float x = s_gT[k * 4 + bl];
            float4 w = *(const float4*)(wp + (size_t)k * 128);
            acc.x += x * w.x; acc.y += x * w.y; acc.z += x * w.z; acc.w += x * w.w;
        }
        *(float4*)&s_part[((bl * 2 + es) * 4 + ks) * 128 + 4 * q] = acc;
    }
    __syncthreads();
    {
        int bl = tid >> 8, es = (tid >> 7) & 1, h = tid & 127;
        int e = s_isel[bl][es];
        float a = eb1[e * 128 + h];
        #pragma unroll
        for (int ks = 0; ks < 4; ++ks)
            a += s_part[((bl * 2 + es) * 4 + ks) * 128 + h];
        ws[WS_U + (size_t)(b0 + bl) * 256 + es * 128 + h] = a;
    }
}

// ---------------------------------------------------------------------------
// C: epilogue over v4 (round-1 version, unchanged).
// ---------------------------------------------------------------------------
__global__ __launch_bounds__(256) void c_kernel(
    const float* __restrict__ eW2, const float* __restrict__ eb2,
    const float* __restrict__ ws, float* __restrict__ pred)
{
    const int b = blockIdx.x >> 2, quad = blockIdx.x & 3, tid = threadIdx.x;

    const float* sel = ws + WS_SEL + (size_t)b * 4;
    const int ea = __builtin_amdgcn_readfirstlane((int)sel[0]);
    const int eb = __builtin_amdgcn_readfirstlane((int)sel[1]);
    const float gA = rfl(sel[2]);
    const float gB = rfl(sel[3]);
    const float bA = eb2[ea], bB = eb2[eb];

    const float* pu = ws + WS_U + (size_t)b * 256;
    const float* wA = eW2 + ea * 128;
    const float* wB = eW2 + eb * 128;

    const int wv = tid >> 6, lane = tid & 63;
    const int tile = quad * 4 + wv;
    const float* vA = ws + WS_V + ((size_t)(tile * 4 + ea)) * 8192 + lane * 4;
    const float* vB = ws + WS_V + ((size_t)(tile * 4 + eb)) * 8192 + lane * 4;

    float dA = 0.f, dB = 0.f;
    #pragma unroll 8
    for (int q = 0; q < 32; ++q) {
        float4 va = *(const float4*)(vA + q * 256);
        float4 ua = *(const float4*)(pu + q * 4);
        float4 wa = *(const float4*)(wA + q * 4);
        dA += fmaxf(ua.x + va.x, 0.f) * wa.x + fmaxf(ua.y + va.y, 0.f) * wa.y
            + fmaxf(ua.z + va.z, 0.f) * wa.z + fmaxf(ua.w + va.w, 0.f) * wa.w;
        float4 vb = *(const float4*)(vB + q * 256);
        float4 ub = *(const float4*)(pu + 128 + q * 4);
        float4 wb = *(const float4*)(wB + q * 4);
        dB += fmaxf(ub.x + vb.x, 0.f) * wb.x + fmaxf(ub.y + vb.y, 0.f) * wb.y
            + fmaxf(ub.z + vb.z, 0.f) * wb.z + fmaxf(ub.w + vb.w, 0.f) * wb.w;
    }
    const int g = tile * 64 + lane;
    if (g < NG) pred[(size_t)b * NG + g] = gA * (dA + bA) + gB * (dB + bB);
}

// ---------------------------------------------------------------------------
extern "C" void kernel_launch(void* const* d_in, const int* in_sizes, int n_in,
                              void* d_out, int out_size, void* d_ws, size_t ws_size,
                              hipStream_t stream) {
    const float* drug  = (const float*)d_in[0];
    const float* gex   = (const float*)d_in[1];
    const float* idose = (const float*)d_in[2];
    const float* cW1 = (const float*)d_in[3];  const float* cb1 = (const float*)d_in[4];
    const float* cW2 = (const float*)d_in[5];  const float* cb2 = (const float*)d_in[6];
    const float* cW3 = (const float*)d_in[7];  const float* cb3 = (const float*)d_in[8];
    const float* dW1 = (const float*)d_in[9];  const float* db1 = (const float*)d_in[10];
    const float* dW2 = (const float*)d_in[11]; const float* db2 = (const float*)d_in[12];
    const float* gene = (const float*)d_in[13];
    const float* gW1 = (const float*)d_in[14]; const float* gb1 = (const float*)d_in[15];
    const float* gW2 = (const float*)d_in[16]; const float* gb2 = (const float*)d_in[17];
    const float* eW1 = (const float*)d_in[18]; const float* eb1 = (const float*)d_in[19];
    const float* eW2 = (const float*)d_in[20]; const float* eb2 = (const float*)d_in[21];

    float* ws   = (float*)d_ws;
    float* out  = (float*)d_out;
    float* pred = out;               // [B, G]
    float* cell = out + NB * NG;     // [B, 50]

    ab_kernel<<<AB_GRID, 1024, 0, stream>>>(drug, gex, idose,
        cW1, cb1, cW2, cb2, cW3, cb3, dW1, db1, dW2, db2,
        gW1, gb1, gW2, gb2, eW1, eb1, gene, ws, cell);
    c_kernel<<<NB * 4, 256, 0, stream>>>(eW2, eb2, ws, pred);
}

// Round 3
// 151.446 us; speedup vs baseline: 1.0393x; 1.0393x over previous
//
#include <hip/hip_runtime.h>

#define NB 256
#define NA 64
#define NG 978
#define CELL_IN 978
#define DOSE_IN 12
#define GLOBAL_F 306
#define EXP_IN 434
#define NE 4

// ---- workspace layout (float offsets) ----
#define WS_SEL 0                        // [256][4] : e1, e2, gate1, gate2
#define WS_U   (WS_SEL + NB*4)          // [256][4][128]  u for ALL experts
#define WS_V   (WS_U + NB*4*128)        // v4[tile16][e4][q32][g64][4h] = 524288
#define WS_GT  (WS_V + 524288)          // gT [306][256]  (g, batch-minor)
#define WS_H1T (WS_GT + GLOBAL_F*NB)    // H1T [200][256]
// total = 1024 + 131072 + 524288 + 78336 + 51200 = 785920 floats (~3.1 MB)

// ---- K1 block ranges ----
#define K1_A0   0       // 256 a-part blocks (v4 producer)
#define K1_C10  256     // 128 cell1 blocks (32 mg x 4 ns)
#define K1_DR0  384     // 256 drug-sum blocks (1/batch)
#define K1_DO0  640     // 32 dose blocks (8 batches each)
#define K1_GRID 672

__device__ __forceinline__ float wave_reduce(float p) {
    #pragma unroll
    for (int off = 32; off > 0; off >>= 1) p += __shfl_down(p, off, 64);
    return p;
}

__device__ __forceinline__ float rfl(float x) {
    return __int_as_float(__builtin_amdgcn_readfirstlane(__float_as_int(x)));
}

// ---------------------------------------------------------------------------
// K1: all leaf computations (mutually independent):
//   [0,256):   a-part — v4 = gene_emb @ eW1_gene  (proven, unchanged)
//   [256,384): cell1  — H1T = relu(gex @ cW1 + b1), block = 8 batches x 50 n
//              (weight slice 196KB/block: per-CU-port friendly)
//   [384,640): drug-sum per batch -> gT rows [0,128)
//   [640,672): dose encoder, 8 batches/block -> gT rows [178,306)
// ---------------------------------------------------------------------------
__global__ __launch_bounds__(1024) void k1_kernel(
    const float* __restrict__ drug, const float* __restrict__ gex,
    const float* __restrict__ idose,
    const float* __restrict__ cW1, const float* __restrict__ cb1,
    const float* __restrict__ dW1, const float* __restrict__ db1,
    const float* __restrict__ dW2, const float* __restrict__ db2,
    const float* __restrict__ eW1, const float* __restrict__ gene,
    float* __restrict__ ws)
{
    __shared__ float smem[14224];      // 56.9 KB -> 2 blocks/CU
    const int blk = blockIdx.x, tid = threadIdx.x;

    if (blk < K1_C10) {
        // ===== a-part: v4[tile][e][q][g][4] =====
        float* s_gene = smem;          // 64*129
        float* s_pu   = smem + 8256;   // [2][512][4]
        const int tile = blk >> 4, e = (blk >> 2) & 3, hq = blk & 3;

        for (int i = tid; i < 64 * 128; i += 1024) {
            int gl = i >> 7, k = i & 127;
            int g = tile * 64 + gl;
            s_gene[gl * 129 + k] = (g < NG) ? gene[g * 128 + k] : 0.f;
        }
        __syncthreads();

        const int g_in  = tid & 63;
        const int slice = (tid >> 6) & 7;
        const int khalf = tid >> 9;
        const int h0 = hq * 32 + slice * 4;
        const float* wbase = eW1
            + ((size_t)e * EXP_IN + GLOBAL_F + khalf * 64) * 128 + h0;
        float4 acc = {0.f, 0.f, 0.f, 0.f};
        #pragma unroll 8
        for (int k = 0; k < 64; ++k) {
            float x = s_gene[g_in * 129 + khalf * 64 + k];
            float4 w = *(const float4*)(wbase + (size_t)k * 128);
            acc.x += x * w.x; acc.y += x * w.y; acc.z += x * w.z; acc.w += x * w.w;
        }
        *(float4*)&s_pu[(khalf * 512 + slice * 64 + g_in) * 4] = acc;
        __syncthreads();
        if (khalf == 0) {
            float4 a0 = *(const float4*)&s_pu[(slice * 64 + g_in) * 4];
            float4 a1 = *(const float4*)&s_pu[(512 + slice * 64 + g_in) * 4];
            float4 r = {a0.x + a1.x, a0.y + a1.y, a0.z + a1.z, a0.w + a1.w};
            const int q = hq * 8 + slice;
            float* vout = ws + WS_V
                + ((size_t)(tile * 4 + e)) * 8192 + q * 256 + g_in * 4;
            *(float4*)vout = r;
        }
        return;
    }

    if (blk < K1_DR0) {
        // ===== cell1: block = (mg of 8 batches, ns of 50 outputs) =====
        const int idx = blk - K1_C10;
        const int mg = idx >> 2, ns = idx & 3;
        const int b0 = mg * 8;
        float* s_x = smem;             // [978][8]
        float* s_p = smem + 7824;      // [16][50][8]

        for (int i = tid; i < CELL_IN * 8; i += 1024) {
            int k = i >> 3, bb = i & 7;
            s_x[i] = gex[(size_t)(b0 + bb) * CELL_IN + k];
        }
        __syncthreads();

        const int ks = tid >> 6, lane = tid & 63;
        if (lane < 50) {
            const int n = ns * 50 + lane;
            int k0 = ks * 62, k1 = min(k0 + 62, CELL_IN);
            float a0=0,a1=0,a2=0,a3=0,a4=0,a5=0,a6=0,a7=0;
            #pragma unroll 4
            for (int k = k0; k < k1; ++k) {
                float w = cW1[(size_t)k * 200 + n];
                float4 xa = *(const float4*)&s_x[k * 8];
                float4 xb = *(const float4*)&s_x[k * 8 + 4];
                a0 += xa.x * w; a1 += xa.y * w; a2 += xa.z * w; a3 += xa.w * w;
                a4 += xb.x * w; a5 += xb.y * w; a6 += xb.z * w; a7 += xb.w * w;
            }
            float* pp = &s_p[(ks * 50 + lane) * 8];
            pp[0]=a0; pp[1]=a1; pp[2]=a2; pp[3]=a3;
            pp[4]=a4; pp[5]=a5; pp[6]=a6; pp[7]=a7;
        }
        __syncthreads();
        if (tid < 400) {
            int n50 = tid >> 3, bb = tid & 7;
            int n = ns * 50 + n50;
            float a = cb1[n];
            #pragma unroll
            for (int k = 0; k < 16; ++k) a += s_p[(k * 50 + n50) * 8 + bb];
            ws[WS_H1T + (size_t)n * NB + b0 + bb] = fmaxf(a, 0.f);
        }
        return;
    }

    if (blk < K1_DO0) {
        // ===== drug atom-sum, one batch -> gT[0..128) =====
        const int b = blk - K1_DR0;
        float* s_red = smem;           // [8][128]
        const int r = tid >> 7, d = tid & 127;
        const float* p = drug + ((size_t)b * NA) * 128 + d;
        float acc = 0.f;
        #pragma unroll
        for (int i = 0; i < 8; ++i) acc += p[(size_t)(i * 8 + r) * 128];
        s_red[r * 128 + d] = acc;
        __syncthreads();
        if (tid < 128) {
            float a = 0.f;
            #pragma unroll
            for (int rr = 0; rr < 8; ++rr) a += s_red[rr * 128 + tid];
            ws[WS_GT + (size_t)tid * NB + b] = a;
        }
        return;
    }

    // ===== dose encoder, 8 batches -> gT[178..306) =====
    {
        const int mg = blk - K1_DO0;
        const int b0 = mg * 8;
        float* s_d1 = smem;            // [8][64]
        const int bb = tid >> 7, j = tid & 127;
        if (j < 64) {
            float acc = db1[j];
            #pragma unroll
            for (int i = 0; i < DOSE_IN; ++i)
                acc += idose[(b0 + bb) * DOSE_IN + i] * dW1[i * 64 + j];
            s_d1[bb * 64 + j] = fmaxf(acc, 0.f);
        }
        __syncthreads();
        float acc = db2[j];
        #pragma unroll 8
        for (int i = 0; i < 64; ++i) acc += s_d1[bb * 64 + i] * dW2[i * 128 + j];
        ws[WS_GT + (size_t)(178 + j) * NB + b0 + bb] = fmaxf(acc, 0.f);
    }
}

// ---------------------------------------------------------------------------
// K2: cell2 + cell3 fused, 32 blocks (8 batches each).
// ---------------------------------------------------------------------------
__global__ __launch_bounds__(1024) void k2_kernel(
    const float* __restrict__ cW2, const float* __restrict__ cb2,
    const float* __restrict__ cW3, const float* __restrict__ cb3,
    float* __restrict__ ws, float* __restrict__ cell_out)
{
    __shared__ float s_x1[200 * 8];
    __shared__ float s_p[8 * 100 * 8];
    __shared__ float s_x2[100 * 8];
    const int mg = blockIdx.x, tid = threadIdx.x;
    const int b0 = mg * 8;

    for (int i = tid; i < 200 * 8; i += 1024) {
        int k = i >> 3, bb = i & 7;
        s_x1[i] = ws[WS_H1T + (size_t)k * NB + b0 + bb];
    }
    __syncthreads();

    // ---- cell2: 200 -> 100 ----
    {
        const int ks = tid >> 7, j = tid & 127;
        if (j < 100) {
            int k0 = ks * 25, k1 = k0 + 25;
            float a0=0,a1=0,a2=0,a3=0,a4=0,a5=0,a6=0,a7=0;
            #pragma unroll 5
            for (int k = k0; k < k1; ++k) {
                float w = cW2[(size_t)k * 100 + j];
                float4 xa = *(const float4*)&s_x1[k * 8];
                float4 xb = *(const float4*)&s_x1[k * 8 + 4];
                a0 += xa.x * w; a1 += xa.y * w; a2 += xa.z * w; a3 += xa.w * w;
                a4 += xb.x * w; a5 += xb.y * w; a6 += xb.z * w; a7 += xb.w * w;
            }
            float* pp = &s_p[(ks * 100 + j) * 8];
            pp[0]=a0; pp[1]=a1; pp[2]=a2; pp[3]=a3;
            pp[4]=a4; pp[5]=a5; pp[6]=a6; pp[7]=a7;
        }
    }
    __syncthreads();
    if (tid < 800) {
        int j = tid >> 3, bb = tid & 7;
        float a = cb2[j];
        #pragma unroll
        for (int k = 0; k < 8; ++k) a += s_p[(k * 100 + j) * 8 + bb];
        s_x2[j * 8 + bb] = fmaxf(a, 0.f);
    }
    __syncthreads();

    // ---- cell3: 100 -> 50 ----
    {
        const int ks = tid >> 7, j = tid & 127;
        if (j < 50) {
            int k0 = ks * 13, k1 = min(k0 + 13, 100);
            float a0=0,a1=0,a2=0,a3=0,a4=0,a5=0,a6=0,a7=0;
            #pragma unroll
            for (int k = k0; k < k1; ++k) {
                float w = cW3[(size_t)k * 50 + j];
                float4 xa = *(const float4*)&s_x2[k * 8];
                float4 xb = *(const float4*)&s_x2[k * 8 + 4];
                a0 += xa.x * w; a1 += xa.y * w; a2 += xa.z * w; a3 += xa.w * w;
                a4 += xb.x * w; a5 += xb.y * w; a6 += xb.z * w; a7 += xb.w * w;
            }
            float* pp = &s_p[(ks * 50 + j) * 8];
            pp[0]=a0; pp[1]=a1; pp[2]=a2; pp[3]=a3;
            pp[4]=a4; pp[5]=a5; pp[6]=a6; pp[7]=a7;
        }
    }
    __syncthreads();
    if (tid < 400) {
        int j = tid >> 3, bb = tid & 7;
        float a = cb3[j];
        #pragma unroll
        for (int k = 0; k < 8; ++k) a += s_p[(k * 50 + j) * 8 + bb];
        float r = fmaxf(a, 0.f);
        ws[WS_GT + (size_t)(128 + j) * NB + b0 + bb] = r;
        cell_out[(b0 + bb) * 50 + j] = r;
    }
}

// ---------------------------------------------------------------------------
// K3: u for ALL 4 experts (128 blocks: 32 mg x 4 e) + gating (32 blocks).
// ---------------------------------------------------------------------------
__global__ __launch_bounds__(1024) void k3_kernel(
    const float* __restrict__ gW1, const float* __restrict__ gb1,
    const float* __restrict__ gW2, const float* __restrict__ gb2,
    const float* __restrict__ eW1, const float* __restrict__ eb1,
    float* __restrict__ ws)
{
    __shared__ float s_g[GLOBAL_F * 8];   // 2448
    __shared__ float s_p[8 * 128 * 8];    // 8192
    __shared__ float s_gh[128 * 8];       // 1024
    const int blk = blockIdx.x, tid = threadIdx.x;
    const bool is_u = blk < 128;
    const int mg = is_u ? (blk >> 2) : (blk - 128);
    const int b0 = mg * 8;

    for (int i = tid; i < GLOBAL_F * 8; i += 1024) {
        int k = i >> 3, bb = i & 7;
        s_g[i] = ws[WS_GT + (size_t)k * NB + b0 + bb];
    }
    __syncthreads();

    if (is_u) {
        const int e = blk & 3;
        {
            const int ks = tid >> 7, h = tid & 127;
            int k0 = ks * 39, k1 = min(k0 + 39, GLOBAL_F);
            float a0=0,a1=0,a2=0,a3=0,a4=0,a5=0,a6=0,a7=0;
            #pragma unroll 4
            for (int k = k0; k < k1; ++k) {
                float w = eW1[((size_t)e * EXP_IN + k) * 128 + h];
                float4 xa = *(const float4*)&s_g[k * 8];
                float4 xb = *(const float4*)&s_g[k * 8 + 4];
                a0 += xa.x * w; a1 += xa.y * w; a2 += xa.z * w; a3 += xa.w * w;
                a4 += xb.x * w; a5 += xb.y * w; a6 += xb.z * w; a7 += xb.w * w;
            }
            float* pp = &s_p[(ks * 128 + h) * 8];
            pp[0]=a0; pp[1]=a1; pp[2]=a2; pp[3]=a3;
            pp[4]=a4; pp[5]=a5; pp[6]=a6; pp[7]=a7;
        }
        __syncthreads();
        {
            int h = tid >> 3, bb = tid & 7;
            float a = eb1[e * 128 + h];
            #pragma unroll
            for (int k = 0; k < 8; ++k) a += s_p[(k * 128 + h) * 8 + bb];
            ws[WS_U + ((size_t)(b0 + bb) * 4 + e) * 128 + h] = a;   // pre-relu
        }
        return;
    }

    // ---- gating ----
    {
        const int ks = tid >> 7, h = tid & 127;
        int k0 = ks * 39, k1 = min(k0 + 39, GLOBAL_F);
        float a0=0,a1=0,a2=0,a3=0,a4=0,a5=0,a6=0,a7=0;
        #pragma unroll 4
        for (int k = k0; k < k1; ++k) {
            float w = gW1[(size_t)k * 128 + h];
            float4 xa = *(const float4*)&s_g[k * 8];
            float4 xb = *(const float4*)&s_g[k * 8 + 4];
            a0 += xa.x * w; a1 += xa.y * w; a2 += xa.z * w; a3 += xa.w * w;
            a4 += xb.x * w; a5 += xb.y * w; a6 += xb.z * w; a7 += xb.w * w;
        }
        float* pp = &s_p[(ks * 128 + h) * 8];
        pp[0]=a0; pp[1]=a1; pp[2]=a2; pp[3]=a3;
        pp[4]=a4; pp[5]=a5; pp[6]=a6; pp[7]=a7;
    }
    __syncthreads();
    {
        int h = tid >> 3, bb = tid & 7;
        float a = gb1[h];
        #pragma unroll
        for (int k = 0; k < 8; ++k) a += s_p[(k * 128 + h) * 8 + bb];
        s_gh[h * 8 + bb] = fmaxf(a, 0.f);
    }
    __syncthreads();
    if (tid < 512) {
        int bb = tid >> 6, lane = tid & 63;
        float h0 = s_gh[lane * 8 + bb], h1 = s_gh[(lane + 64) * 8 + bb];
        float logit[NE];
        #pragma unroll
        for (int j = 0; j < NE; ++j) {
            float p = h0 * gW2[lane * NE + j] + h1 * gW2[(lane + 64) * NE + j];
            p = wave_reduce(p);
            logit[j] = p + gb2[j];
        }
        if (lane == 0) {
            int i1 = 0; float v1 = logit[0];
            #pragma unroll
            for (int i = 1; i < NE; ++i) if (logit[i] > v1) { v1 = logit[i]; i1 = i; }
            int i2 = -1; float v2 = -__builtin_inff();
            #pragma unroll
            for (int i = 0; i < NE; ++i) {
                if (i == i1) continue;
                if (logit[i] > v2) { v2 = logit[i]; i2 = i; }
            }
            float ex = __expf(v2 - v1);
            float inv = 1.f / (1.f + ex);
            int bg = b0 + bb;
            ws[WS_SEL + bg * 4 + 0] = (float)i1;
            ws[WS_SEL + bg * 4 + 1] = (float)i2;
            ws[WS_SEL + bg * 4 + 2] = inv;
            ws[WS_SEL + bg * 4 + 3] = ex * inv;
        }
    }
}

// ---------------------------------------------------------------------------
// C: epilogue over v4 (round-1 version; u now indexed [b][4][128]).
// ---------------------------------------------------------------------------
__global__ __launch_bounds__(256) void c_kernel(
    const float* __restrict__ eW2, const float* __restrict__ eb2,
    const float* __restrict__ ws, float* __restrict__ pred)
{
    const int b = blockIdx.x >> 2, quad = blockIdx.x & 3, tid = threadIdx.x;

    const float* sel = ws + WS_SEL + (size_t)b * 4;
    const int ea = __builtin_amdgcn_readfirstlane((int)sel[0]);
    const int eb = __builtin_amdgcn_readfirstlane((int)sel[1]);
    const float gA = rfl(sel[2]);
    const float gB = rfl(sel[3]);
    const float bA = eb2[ea], bB = eb2[eb];

    const float* uA = ws + WS_U + ((size_t)b * 4 + ea) * 128;
    const float* uB = ws + WS_U + ((size_t)b * 4 + eb) * 128;
    const float* wA = eW2 + ea * 128;
    const float* wB = eW2 + eb * 128;

    const int wv = tid >> 6, lane = tid & 63;
    const int tile = quad * 4 + wv;
    const float* vA = ws + WS_V + ((size_t)(tile * 4 + ea)) * 8192 + lane * 4;
    const float* vB = ws + WS_V + ((size_t)(tile * 4 + eb)) * 8192 + lane * 4;

    float dA = 0.f, dB = 0.f;
    #pragma unroll 8
    for (int q = 0; q < 32; ++q) {
        float4 va = *(const float4*)(vA + q * 256);
        float4 ua = *(const float4*)(uA + q * 4);
        float4 wa = *(const float4*)(wA + q * 4);
        dA += fmaxf(ua.x + va.x, 0.f) * wa.x + fmaxf(ua.y + va.y, 0.f) * wa.y
            + fmaxf(ua.z + va.z, 0.f) * wa.z + fmaxf(ua.w + va.w, 0.f) * wa.w;
        float4 vb = *(const float4*)(vB + q * 256);
        float4 ub = *(const float4*)(uB + q * 4);
        float4 wb = *(const float4*)(wB + q * 4);
        dB += fmaxf(ub.x + vb.x, 0.f) * wb.x + fmaxf(ub.y + vb.y, 0.f) * wb.y
            + fmaxf(ub.z + vb.z, 0.f) * wb.z + fmaxf(ub.w + vb.w, 0.f) * wb.w;
    }
    const int g = tile * 64 + lane;
    if (g < NG) pred[(size_t)b * NG + g] = gA * (dA + bA) + gB * (dB + bB);
}

// ---------------------------------------------------------------------------
extern "C" void kernel_launch(void* const* d_in, const int* in_sizes, int n_in,
                              void* d_out, int out_size, void* d_ws, size_t ws_size,
                              hipStream_t stream) {
    const float* drug  = (const float*)d_in[0];
    const float* gex   = (const float*)d_in[1];
    const float* idose = (const float*)d_in[2];
    const float* cW1 = (const float*)d_in[3];  const float* cb1 = (const float*)d_in[4];
    const float* cW2 = (const float*)d_in[5];  const float* cb2 = (const float*)d_in[6];
    const float* cW3 = (const float*)d_in[7];  const float* cb3 = (const float*)d_in[8];
    const float* dW1 = (const float*)d_in[9];  const float* db1 = (const float*)d_in[10];
    const float* dW2 = (const float*)d_in[11]; const float* db2 = (const float*)d_in[12];
    const float* gene = (const float*)d_in[13];
    const float* gW1 = (const float*)d_in[14]; const float* gb1 = (const float*)d_in[15];
    const float* gW2 = (const float*)d_in[16]; const float* gb2 = (const float*)d_in[17];
    const float* eW1 = (const float*)d_in[18]; const float* eb1 = (const float*)d_in[19];
    const float* eW2 = (const float*)d_in[20]; const float* eb2 = (const float*)d_in[21];

    float* ws   = (float*)d_ws;
    float* out  = (float*)d_out;
    float* pred = out;               // [B, G]
    float* cell = out + NB * NG;     // [B, 50]

    k1_kernel<<<K1_GRID, 1024, 0, stream>>>(drug, gex, idose,
        cW1, cb1, dW1, db1, dW2, db2, eW1, gene, ws);
    k2_kernel<<<32, 1024, 0, stream>>>(cW2, cb2, cW3, cb3, ws, cell);
    k3_kernel<<<160, 1024, 0, stream>>>(gW1, gb1, gW2, gb2, eW1, eb1, ws);
    c_kernel<<<NB * 4, 256, 0, stream>>>(eW2, eb2, ws, pred);
}